// Round 6
// baseline (4302.361 us; speedup 1.0000x reference)
//
#include <hip/hip_runtime.h>

// LSTM decoder B=64,S=512,D=512,H=512,L=2 — Round 6: persistent kernel,
// per-group (ms) all-to-all flag barrier: 4 independent groups of 64 blocks,
// each block posts one sc1 flag, wave0 polls its group's 64 flags (1 lane each,
// one coalesced 256B load per poll). Single L3 hop per step.
// h traffic via relaxed agent atomics (sc1, no cache maintenance) as R5.
// role0 prefetches x(t+1) into registers before the barrier.

#define NB 64
#define NS 512
#define ND 512
#define NH 512

typedef __attribute__((ext_vector_type(8))) short short8;
typedef __attribute__((ext_vector_type(4))) float f32x4;

// ---- ws layout (bytes) ----
#define WPK_OFF   0                 // 2 roles * 128nt * 32k0i * 512 bf16 = 8,388,608
#define H0B0_OFF  8388608           // bf16 64*512 = 65536
#define H0B1_OFF  8454144
#define H1B0_OFF  8519680
#define H1B1_OFF  8585216
#define FLAGS_OFF 8650752           // 4 groups * 64 flags * 4B = 1024
#define WPK_ELEMS_PER_ROLE (128 * 32 * 512)

__device__ __forceinline__ unsigned int pack2bf(float a, float b) {
    unsigned int ua = __builtin_bit_cast(unsigned int, a);
    unsigned int ub = __builtin_bit_cast(unsigned int, b);
    ua += 0x7fffu + ((ua >> 16) & 1u);   // RNE
    ub += 0x7fffu + ((ub >> 16) & 1u);
    return (ua >> 16) | (ub & 0xffff0000u);
}
__device__ __forceinline__ unsigned short bf16r(float a) {
    unsigned int ua = __builtin_bit_cast(unsigned int, a);
    ua += 0x7fffu + ((ua >> 16) & 1u);
    return (unsigned short)(ua >> 16);
}

// L3-coherent primitives (relaxed agent atomics -> sc1, no cache maintenance)
__device__ __forceinline__ unsigned long long ld_h64(const void* p) {
    return __hip_atomic_load((const unsigned long long*)p, __ATOMIC_RELAXED,
                             __HIP_MEMORY_SCOPE_AGENT);
}
__device__ __forceinline__ void st_h32(void* p, unsigned int v) {
    __hip_atomic_store((unsigned int*)p, v, __ATOMIC_RELAXED,
                       __HIP_MEMORY_SCOPE_AGENT);
}
__device__ __forceinline__ unsigned int ld_flag(const unsigned int* p) {
    return __hip_atomic_load(p, __ATOMIC_RELAXED, __HIP_MEMORY_SCOPE_AGENT);
}
__device__ __forceinline__ void st_flag(unsigned int* p, unsigned int v) {
    __hip_atomic_store(p, v, __ATOMIC_RELAXED, __HIP_MEMORY_SCOPE_AGENT);
}

// Repack weights into MFMA B-fragment order:
// fragment (r, nt, k0i), lane l, elem j: B[k][n], n = nt*16+(l&15), k = k0i*32+(l>>4)*8+j
// k<512 -> W_ih[r][n][k], else W_hh[r][n][k-512]
__global__ void prep_weights_k(const float* __restrict__ W_ih,
                               const float* __restrict__ W_hh,
                               unsigned int* __restrict__ wpk_u32) {
    long long gid = (long long)blockIdx.x * blockDim.x + threadIdx.x; // 524288
    int l   = (int)(gid & 63);
    int k0i = (int)((gid >> 6) & 31);
    int nt  = (int)((gid >> 11) & 127);
    int r   = (int)(gid >> 18);
    int n = nt * 16 + (l & 15);
    int k = k0i * 32 + ((l >> 4) << 3);
    const float* src;
    if (k < 512) src = W_ih + ((long long)r * 2048 + n) * 512 + k;
    else         src = W_hh + ((long long)r * 2048 + n) * 512 + (k - 512);
    uint4 v;
    v.x = pack2bf(src[0], src[1]);
    v.y = pack2bf(src[2], src[3]);
    v.z = pack2bf(src[4], src[5]);
    v.w = pack2bf(src[6], src[7]);
    ((uint4*)wpk_u32)[gid] = v;
}

__global__ void prep_state_k(const float* __restrict__ eh,
                             unsigned short* __restrict__ h0b0,
                             unsigned short* __restrict__ h1b0,
                             unsigned int* __restrict__ flags) {
    int i = blockIdx.x * blockDim.x + threadIdx.x;  // 32768
    if (i < NB * NH) {
        unsigned short hb = bf16r(eh[i]);
        h0b0[i] = hb;
        h1b0[i] = hb;
    }
    if (i < 256) flags[i] = 0;
}

__global__ __launch_bounds__(256, 2)
void lstm_persist_k(const float* __restrict__ input,
                    const float* __restrict__ enc_c,
                    const float* __restrict__ b_ih,
                    const float* __restrict__ b_hh,
                    const unsigned short* __restrict__ wpk,
                    unsigned short* __restrict__ h0b0,
                    unsigned short* __restrict__ h0b1,
                    unsigned short* __restrict__ h1b0,
                    unsigned short* __restrict__ h1b1,
                    float* __restrict__ out,
                    unsigned int* __restrict__ flags) {
    __shared__ alignas(16) unsigned char smem[32768];
    const int bid  = blockIdx.x;
    const int role = bid >> 7;             // 0: layer0(t), 1: layer1(t-1)
    const int lb   = bid & 127;
    const int ms   = lb >> 5;              // batch block 0..3 (sync group)
    const int us   = lb & 31;              // unit block 0..31
    const int m0   = ms << 4;
    const int tid  = threadIdx.x;
    const int lane = tid & 63;
    const int tq   = tid >> 6;
    const int g    = __builtin_amdgcn_readfirstlane(tq);  // wave = gate

    const unsigned short* wp = wpk + (long long)role * WPK_ELEMS_PER_ROLE
                                   + (long long)(g * 32 + us) * (32 * 512);
    unsigned int* myflag   = flags + (ms << 6) + (role << 5) + us;
    const unsigned int* gf = flags + (ms << 6) + lane;

    // ---- per-thread cell state + biases (plain cached loads, once) ----
    const int m_l = tid >> 4, u_l = tid & 15;
    const int bcell = m0 + m_l;
    const int ucell = us * 16 + u_l;
    float cReg = enc_c[bcell * NH + ucell];
    const long long br = (long long)role * 2048;
    const float bias_i = b_ih[br + 0 * 512 + ucell] + b_hh[br + 0 * 512 + ucell];
    const float bias_f = b_ih[br + 1 * 512 + ucell] + b_hh[br + 1 * 512 + ucell];
    const float bias_g = b_ih[br + 2 * 512 + ucell] + b_hh[br + 2 * 512 + ucell];
    const float bias_o = b_ih[br + 3 * 512 + ucell] + b_hh[br + 3 * 512 + ucell];

    unsigned short* h0b[2] = { h0b0, h0b1 };
    unsigned short* h1b[2] = { h1b0, h1b1 };

    // ---- role0: prefetch x(0) into registers ----
    float4 xp[8];
    if (role == 0) {
        #pragma unroll
        for (int i = 0; i < 4; ++i) {
            int k0i = i * 4 + tq;
            const float* s = input + (long long)(m0 + (lane & 15)) * (NS * ND)
                                   + 0 * ND + k0i * 32 + ((lane >> 4) << 3);
            xp[2 * i]     = *(const float4*)s;
            xp[2 * i + 1] = *(const float4*)(s + 4);
        }
    }

    for (int t = 0; t <= NS; ++t) {
        const bool active = (role == 0) ? (t < NS) : (t >= 1);
        if (active) {
            const unsigned short* xh = h0b[t & 1];
            const unsigned short* hp = (role == 0) ? h0b[t & 1] : h1b[(t + 1) & 1];

            // ---- stage A (16 rows x K=1024 bf16, fragment-packed) ----
            // x-part (i=0..3): role0 packs prefetched regs; role1 sc1 from h0.
            // h-part (i=4..7): sc1 from h buffers.
            #pragma unroll
            for (int i = 0; i < 8; ++i) {
                int sid = i * 256 + tid;
                int k0i = sid >> 6;
                int m   = m0 + (lane & 15);
                int kk  = (lane >> 4) << 3;
                uint4 val;
                if (i < 4) {
                    if (role == 0) {
                        float4 lo = xp[2 * i], hi = xp[2 * i + 1];
                        val.x = pack2bf(lo.x, lo.y);
                        val.y = pack2bf(lo.z, lo.w);
                        val.z = pack2bf(hi.x, hi.y);
                        val.w = pack2bf(hi.z, hi.w);
                    } else {
                        int k = k0i * 32 + kk;
                        const unsigned long long* p =
                            (const unsigned long long*)(xh + (long long)m * 512 + k);
                        unsigned long long lo = ld_h64(p);
                        unsigned long long hi = ld_h64(p + 1);
                        val.x = (unsigned int)lo; val.y = (unsigned int)(lo >> 32);
                        val.z = (unsigned int)hi; val.w = (unsigned int)(hi >> 32);
                    }
                } else {
                    int k = (k0i - 16) * 32 + kk;
                    const unsigned long long* p =
                        (const unsigned long long*)(hp + (long long)m * 512 + k);
                    unsigned long long lo = ld_h64(p);
                    unsigned long long hi = ld_h64(p + 1);
                    val.x = (unsigned int)lo; val.y = (unsigned int)(lo >> 32);
                    val.z = (unsigned int)hi; val.w = (unsigned int)(hi >> 32);
                }
                *(uint4*)(smem + sid * 16) = val;
            }
            __syncthreads();

            // ---- GEMM: 32 MFMAs, 4 acc chains; weights from warm local L2 ----
            f32x4 acc0 = {0.f,0.f,0.f,0.f}, acc1 = {0.f,0.f,0.f,0.f};
            f32x4 acc2 = {0.f,0.f,0.f,0.f}, acc3 = {0.f,0.f,0.f,0.f};
            #pragma unroll
            for (int k0i = 0; k0i < 32; k0i += 4) {
                short8 a0 = *(const short8*)(smem + (k0i + 0) * 1024 + lane * 16);
                short8 a1 = *(const short8*)(smem + (k0i + 1) * 1024 + lane * 16);
                short8 a2 = *(const short8*)(smem + (k0i + 2) * 1024 + lane * 16);
                short8 a3 = *(const short8*)(smem + (k0i + 3) * 1024 + lane * 16);
                short8 b0 = *(const short8*)(wp + (k0i + 0) * 512 + lane * 8);
                short8 b1 = *(const short8*)(wp + (k0i + 1) * 512 + lane * 8);
                short8 b2 = *(const short8*)(wp + (k0i + 2) * 512 + lane * 8);
                short8 b3 = *(const short8*)(wp + (k0i + 3) * 512 + lane * 8);
                acc0 = __builtin_amdgcn_mfma_f32_16x16x32_bf16(a0, b0, acc0, 0, 0, 0);
                acc1 = __builtin_amdgcn_mfma_f32_16x16x32_bf16(a1, b1, acc1, 0, 0, 0);
                acc2 = __builtin_amdgcn_mfma_f32_16x16x32_bf16(a2, b2, acc2, 0, 0, 0);
                acc3 = __builtin_amdgcn_mfma_f32_16x16x32_bf16(a3, b3, acc3, 0, 0, 0);
            }
            f32x4 accS = (acc0 + acc1) + (acc2 + acc3);
            __syncthreads();   // done reading A; reuse smem for gates

            float (*Gs)[16][17] = (float (*)[16][17])smem;
            {
                int u_g  = lane & 15;
                int mrow = (lane >> 4) * 4;
                #pragma unroll
                for (int r = 0; r < 4; ++r)
                    Gs[g][mrow + r][u_g] = accS[r];
            }
            __syncthreads();

            // ---- fused LSTM cell (1 cell/thread, c stays in register) ----
            {
                float gi = Gs[0][m_l][u_l] + bias_i;
                float gf = Gs[1][m_l][u_l] + bias_f;
                float gg = Gs[2][m_l][u_l] + bias_g;
                float go = Gs[3][m_l][u_l] + bias_o;
                float ii = 1.f / (1.f + expf(-gi));
                float ff = 1.f / (1.f + expf(-gf));
                float gv = tanhf(gg);
                float oo = 1.f / (1.f + expf(-go));
                cReg = ff * cReg + ii * gv;
                float hn = oo * tanhf(cReg);

                // publish h (packed bf16 pair) via sc1 store
                float hn_p = __shfl_xor(hn, 1);
                if ((u_l & 1) == 0) {
                    unsigned int pk = pack2bf(hn, hn_p);
                    unsigned short* hbuf = (role == 0) ? h0b[(t + 1) & 1] : h1b[t & 1];
                    st_h32((unsigned int*)hbuf + ((bcell * NH + ucell) >> 1), pk);
                }
                if (role == 1) {
                    int s = t - 1;
                    out[(long long)bcell * (NS * NH) + (long long)s * NH + ucell] = hn;
                    if (t == NS) {
                        float* dst = out + (long long)NB * NS * NH;
                        dst[bcell * NH + ucell] = hn;
                        dst[NB * NH + bcell * NH + ucell] = cReg;
                    }
                }
            }
        }

        if (t < NS) {
            // ---- role0: prefetch x(t+1) before waiting (h-independent) ----
            if (role == 0 && t + 1 < NS) {
                #pragma unroll
                for (int i = 0; i < 4; ++i) {
                    int k0i = i * 4 + tq;
                    const float* s = input + (long long)(m0 + (lane & 15)) * (NS * ND)
                                           + (long long)(t + 1) * ND
                                           + k0i * 32 + ((lane >> 4) << 3);
                    xp[2 * i]     = *(const float4*)s;
                    xp[2 * i + 1] = *(const float4*)(s + 4);
                }
            }

            // ---- group all-to-all barrier: 1 L3 hop ----
            // __syncthreads drains each wave's vmcnt -> h stores acked at L3
            // before the flag store issues.
            const unsigned int epoch = (unsigned int)(t + 1);
            __syncthreads();
            if (tid == 0) st_flag(myflag, epoch);
            if (tid < 64) {
                for (;;) {
                    unsigned int v = ld_flag(gf);
                    if (__ballot(v >= epoch) == 0xFFFFFFFFFFFFFFFFULL) break;
                    __builtin_amdgcn_s_sleep(2);
                }
            }
            __syncthreads();
        }
    }
}

extern "C" void kernel_launch(void* const* d_in, const int* in_sizes, int n_in,
                              void* d_out, int out_size, void* d_ws, size_t ws_size,
                              hipStream_t stream) {
    const float* input = (const float*)d_in[0];
    const float* enc_h = (const float*)d_in[1];
    const float* enc_c = (const float*)d_in[2];
    const float* W_ih  = (const float*)d_in[3];
    const float* W_hh  = (const float*)d_in[4];
    const float* b_ih  = (const float*)d_in[5];
    const float* b_hh  = (const float*)d_in[6];
    float* out = (float*)d_out;
    unsigned char* ws = (unsigned char*)d_ws;

    unsigned short* wpk   = (unsigned short*)(ws + WPK_OFF);
    unsigned short* h0b0  = (unsigned short*)(ws + H0B0_OFF);
    unsigned short* h0b1  = (unsigned short*)(ws + H0B1_OFF);
    unsigned short* h1b0  = (unsigned short*)(ws + H1B0_OFF);
    unsigned short* h1b1  = (unsigned short*)(ws + H1B1_OFF);
    unsigned int*   flags = (unsigned int*)(ws + FLAGS_OFF);

    prep_weights_k<<<2048, 256, 0, stream>>>(W_ih, W_hh, (unsigned int*)wpk);
    prep_state_k<<<128, 256, 0, stream>>>(enc_h, h0b0, h1b0, flags);
    lstm_persist_k<<<256, 256, 0, stream>>>(input, enc_c, b_ih, b_hh, wpk,
                                            h0b0, h0b1, h1b0, h1b1, out, flags);
}

// Round 7
// 2653.536 us; speedup vs baseline: 1.6214x; 1.6214x over previous
//
#include <hip/hip_runtime.h>

// LSTM decoder B=64,S=512,D=512,H=512,L=2 — Round 7: persistent kernel,
// dataflow barrier: per-(ms) group epoch flags, role-asymmetric waits,
// h0 4-deep / h1 2-deep buffers, flag posted before x-prefetch, role0
// pre-stages x into LDS before polling. sc1 (L3) h traffic, no fences.

#define NB 64
#define NS 512
#define ND 512
#define NH 512

typedef __attribute__((ext_vector_type(8))) short short8;
typedef __attribute__((ext_vector_type(4))) float f32x4;

// ---- ws layout (bytes) ----
#define WPK_OFF   0                 // 8,388,608
#define H0_OFF    8388608           // 4 bufs * 65536
#define H1_OFF    8650752           // 2 bufs * 65536
#define FLAGS_OFF 8781824           // 256 u32
#define WPK_ELEMS_PER_ROLE (128 * 32 * 512)

__device__ __forceinline__ unsigned int pack2bf(float a, float b) {
    unsigned int ua = __builtin_bit_cast(unsigned int, a);
    unsigned int ub = __builtin_bit_cast(unsigned int, b);
    ua += 0x7fffu + ((ua >> 16) & 1u);   // RNE
    ub += 0x7fffu + ((ub >> 16) & 1u);
    return (ua >> 16) | (ub & 0xffff0000u);
}
__device__ __forceinline__ unsigned short bf16r(float a) {
    unsigned int ua = __builtin_bit_cast(unsigned int, a);
    ua += 0x7fffu + ((ua >> 16) & 1u);
    return (unsigned short)(ua >> 16);
}

// L3-coherent primitives (relaxed agent atomics -> sc1, no cache maintenance)
__device__ __forceinline__ unsigned long long ld_h64(const void* p) {
    return __hip_atomic_load((const unsigned long long*)p, __ATOMIC_RELAXED,
                             __HIP_MEMORY_SCOPE_AGENT);
}
__device__ __forceinline__ void st_h32(void* p, unsigned int v) {
    __hip_atomic_store((unsigned int*)p, v, __ATOMIC_RELAXED,
                       __HIP_MEMORY_SCOPE_AGENT);
}
__device__ __forceinline__ unsigned int ld_flag(const unsigned int* p) {
    return __hip_atomic_load(p, __ATOMIC_RELAXED, __HIP_MEMORY_SCOPE_AGENT);
}
__device__ __forceinline__ void st_flag(unsigned int* p, unsigned int v) {
    __hip_atomic_store(p, v, __ATOMIC_RELAXED, __HIP_MEMORY_SCOPE_AGENT);
}

// Repack weights into MFMA B-fragment order:
// fragment (r, nt, k0i), lane l, elem j: B[k][n], n = nt*16+(l&15), k = k0i*32+(l>>4)*8+j
__global__ void prep_weights_k(const float* __restrict__ W_ih,
                               const float* __restrict__ W_hh,
                               unsigned int* __restrict__ wpk_u32) {
    long long gid = (long long)blockIdx.x * blockDim.x + threadIdx.x; // 524288
    int l   = (int)(gid & 63);
    int k0i = (int)((gid >> 6) & 31);
    int nt  = (int)((gid >> 11) & 127);
    int r   = (int)(gid >> 18);
    int n = nt * 16 + (l & 15);
    int k = k0i * 32 + ((l >> 4) << 3);
    const float* src;
    if (k < 512) src = W_ih + ((long long)r * 2048 + n) * 512 + k;
    else         src = W_hh + ((long long)r * 2048 + n) * 512 + (k - 512);
    uint4 v;
    v.x = pack2bf(src[0], src[1]);
    v.y = pack2bf(src[2], src[3]);
    v.z = pack2bf(src[4], src[5]);
    v.w = pack2bf(src[6], src[7]);
    ((uint4*)wpk_u32)[gid] = v;
}

__global__ void prep_state_k(const float* __restrict__ eh,
                             unsigned short* __restrict__ h0base,
                             unsigned short* __restrict__ h1base,
                             unsigned int* __restrict__ flags) {
    int i = blockIdx.x * blockDim.x + threadIdx.x;  // 32768
    if (i < NB * NH) {
        unsigned short hb = bf16r(eh[i]);
        (h0base + 3 * 32768)[i] = hb;   // h0_{-1} -> buf[(-1)&3] = 3
        (h1base + 1 * 32768)[i] = hb;   // h1_{-1} -> buf[(-1)&1] = 1
    }
    if (i < 256) flags[i] = 0;
}

__global__ __launch_bounds__(256, 2)
void lstm_persist_k(const float* __restrict__ input,
                    const float* __restrict__ enc_c,
                    const float* __restrict__ b_ih,
                    const float* __restrict__ b_hh,
                    const unsigned short* __restrict__ wpk,
                    unsigned short* __restrict__ h0base,
                    unsigned short* __restrict__ h1base,
                    float* __restrict__ out,
                    unsigned int* __restrict__ flags) {
    __shared__ alignas(16) unsigned char smem[32768];
    const int bid  = blockIdx.x;
    const int role = bid >> 7;             // 0: layer0(t=i), 1: layer1(s=i-1)
    const int lb   = bid & 127;
    const int ms   = lb >> 5;              // batch block 0..3 (sync group)
    const int us   = lb & 31;              // unit block 0..31
    const int m0   = ms << 4;
    const int tid  = threadIdx.x;
    const int lane = tid & 63;
    const int tq   = tid >> 6;
    const int g    = __builtin_amdgcn_readfirstlane(tq);  // wave = gate

    const unsigned short* wp = wpk + (long long)role * WPK_ELEMS_PER_ROLE
                                   + (long long)(g * 32 + us) * (32 * 512);
    unsigned int* myflag   = flags + (ms << 6) + (role << 5) + us;
    const unsigned int* gf = flags + (ms << 6) + lane;

    // ---- per-thread cell state + biases (plain cached loads, once) ----
    const int m_l = tid >> 4, u_l = tid & 15;
    const int bcell = m0 + m_l;
    const int ucell = us * 16 + u_l;
    float cReg = enc_c[bcell * NH + ucell];
    const long long br = (long long)role * 2048;
    const float bias_i = b_ih[br + 0 * 512 + ucell] + b_hh[br + 0 * 512 + ucell];
    const float bias_f = b_ih[br + 1 * 512 + ucell] + b_hh[br + 1 * 512 + ucell];
    const float bias_g = b_ih[br + 2 * 512 + ucell] + b_hh[br + 2 * 512 + ucell];
    const float bias_o = b_ih[br + 3 * 512 + ucell] + b_hh[br + 3 * 512 + ucell];

    // ---- role0: prefetch x(0) into registers ----
    float4 xp[8];
    if (role == 0) {
        #pragma unroll
        for (int ii = 0; ii < 4; ++ii) {
            int k0i = ii * 4 + tq;
            const float* s = input + (long long)(m0 + (lane & 15)) * (NS * ND)
                                   + k0i * 32 + ((lane >> 4) << 3);
            xp[2 * ii]     = *(const float4*)s;
            xp[2 * ii + 1] = *(const float4*)(s + 4);
        }
    }

    for (int i = 0; i <= NS; ++i) {
        const bool active = (role == 0) ? (i < NS) : (i >= 1);

        // ---- A: role0 pre-poll x staging (regs -> LDS x-region) ----
        if (role == 0 && i < NS) {
            #pragma unroll
            for (int ii = 0; ii < 4; ++ii) {
                int sid = ii * 256 + tid;
                float4 lo = xp[2 * ii], hi = xp[2 * ii + 1];
                uint4 val;
                val.x = pack2bf(lo.x, lo.y);
                val.y = pack2bf(lo.z, lo.w);
                val.z = pack2bf(hi.x, hi.y);
                val.w = pack2bf(hi.z, hi.w);
                *(uint4*)(smem + sid * 16) = val;
            }
        }

        // ---- B: poll (role-asymmetric epochs) ----
        if (i > 0) {
            if (tid < 64) {
                unsigned int thr;
                if (role == 0)
                    thr = (lane < 32) ? (unsigned int)i
                                      : (unsigned int)(i >= 2 ? i - 2 : 0);
                else
                    thr = (unsigned int)i;
                for (;;) {
                    unsigned int v = ld_flag(gf);
                    if (__ballot(v >= thr) == 0xFFFFFFFFFFFFFFFFULL) break;
                    __builtin_amdgcn_s_sleep(1);
                }
            }
            __syncthreads();   // flag observed -> safe to read h data
        }

        if (active) {
            const unsigned short* h0prev = h0base + (((i - 1) & 3) << 15); // h0_{i-1}
            const unsigned short* hp = (role == 0) ? h0prev
                                     : h1base + ((i & 1) << 15);          // h1_{i-2}

            // ---- C: stage remaining A-parts ----
            if (role == 1) {
                // x-part = h0_{i-1}
                #pragma unroll
                for (int ii = 0; ii < 4; ++ii) {
                    int sid = ii * 256 + tid;
                    int k0i = sid >> 6;
                    int m   = m0 + (lane & 15);
                    int k   = k0i * 32 + ((lane >> 4) << 3);
                    const unsigned long long* p =
                        (const unsigned long long*)(h0prev + (long long)m * 512 + k);
                    unsigned long long lo = ld_h64(p);
                    unsigned long long hi = ld_h64(p + 1);
                    uint4 val;
                    val.x = (unsigned int)lo; val.y = (unsigned int)(lo >> 32);
                    val.z = (unsigned int)hi; val.w = (unsigned int)(hi >> 32);
                    *(uint4*)(smem + sid * 16) = val;
                }
            }
            // h-part (both roles)
            #pragma unroll
            for (int ii = 4; ii < 8; ++ii) {
                int sid = ii * 256 + tid;
                int k0i = sid >> 6;
                int m   = m0 + (lane & 15);
                int k   = (k0i - 16) * 32 + ((lane >> 4) << 3);
                const unsigned long long* p =
                    (const unsigned long long*)(hp + (long long)m * 512 + k);
                unsigned long long lo = ld_h64(p);
                unsigned long long hi = ld_h64(p + 1);
                uint4 val;
                val.x = (unsigned int)lo; val.y = (unsigned int)(lo >> 32);
                val.z = (unsigned int)hi; val.w = (unsigned int)(hi >> 32);
                *(uint4*)(smem + sid * 16) = val;
            }
            __syncthreads();

            // ---- GEMM: 32 MFMAs, 4 acc chains; weights from warm local L2 ----
            f32x4 acc0 = {0.f,0.f,0.f,0.f}, acc1 = {0.f,0.f,0.f,0.f};
            f32x4 acc2 = {0.f,0.f,0.f,0.f}, acc3 = {0.f,0.f,0.f,0.f};
            #pragma unroll
            for (int k0i = 0; k0i < 32; k0i += 4) {
                short8 a0 = *(const short8*)(smem + (k0i + 0) * 1024 + lane * 16);
                short8 a1 = *(const short8*)(smem + (k0i + 1) * 1024 + lane * 16);
                short8 a2 = *(const short8*)(smem + (k0i + 2) * 1024 + lane * 16);
                short8 a3 = *(const short8*)(smem + (k0i + 3) * 1024 + lane * 16);
                short8 b0 = *(const short8*)(wp + (k0i + 0) * 512 + lane * 8);
                short8 b1 = *(const short8*)(wp + (k0i + 1) * 512 + lane * 8);
                short8 b2 = *(const short8*)(wp + (k0i + 2) * 512 + lane * 8);
                short8 b3 = *(const short8*)(wp + (k0i + 3) * 512 + lane * 8);
                acc0 = __builtin_amdgcn_mfma_f32_16x16x32_bf16(a0, b0, acc0, 0, 0, 0);
                acc1 = __builtin_amdgcn_mfma_f32_16x16x32_bf16(a1, b1, acc1, 0, 0, 0);
                acc2 = __builtin_amdgcn_mfma_f32_16x16x32_bf16(a2, b2, acc2, 0, 0, 0);
                acc3 = __builtin_amdgcn_mfma_f32_16x16x32_bf16(a3, b3, acc3, 0, 0, 0);
            }
            f32x4 accS = (acc0 + acc1) + (acc2 + acc3);
            __syncthreads();   // done reading A; reuse smem for gates

            float (*Gs)[16][17] = (float (*)[16][17])smem;
            {
                int u_g  = lane & 15;
                int mrow = (lane >> 4) * 4;
                #pragma unroll
                for (int r = 0; r < 4; ++r)
                    Gs[g][mrow + r][u_g] = accS[r];
            }
            __syncthreads();

            // ---- fused LSTM cell (1 cell/thread, c stays in register) ----
            {
                float gi = Gs[0][m_l][u_l] + bias_i;
                float gf = Gs[1][m_l][u_l] + bias_f;
                float gg = Gs[2][m_l][u_l] + bias_g;
                float go = Gs[3][m_l][u_l] + bias_o;
                float ii = 1.f / (1.f + expf(-gi));
                float ff = 1.f / (1.f + expf(-gf));
                float gv = tanhf(gg);
                float oo = 1.f / (1.f + expf(-go));
                cReg = ff * cReg + ii * gv;
                float hn = oo * tanhf(cReg);

                // publish h (packed bf16 pair) via sc1 store
                float hn_p = __shfl_xor(hn, 1);
                if ((u_l & 1) == 0) {
                    unsigned int pk = pack2bf(hn, hn_p);
                    unsigned short* hbuf = (role == 0)
                        ? h0base + ((i & 3) << 15)             // h0_i
                        : h1base + (((i - 1) & 1) << 15);      // h1_{i-1}
                    st_h32((unsigned int*)hbuf + ((bcell * NH + ucell) >> 1), pk);
                }
                if (role == 1) {
                    int s = i - 1;
                    out[(long long)bcell * (NS * NH) + (long long)s * NH + ucell] = hn;
                    if (i == NS) {
                        float* dst = out + (long long)NB * NS * NH;
                        dst[bcell * NH + ucell] = hn;
                        dst[NB * NH + bcell * NH + ucell] = cReg;
                    }
                }
            }
        }

        // ---- D: publish flag FIRST, then prefetch next x ----
        if (i < NS) {
            __syncthreads();   // drains vmcnt per wave -> h stores acked at L3
            if (tid == 0) st_flag(myflag, (unsigned int)(i + 1));
            if (role == 0 && i + 1 < NS) {
                #pragma unroll
                for (int ii = 0; ii < 4; ++ii) {
                    int k0i = ii * 4 + tq;
                    const float* s = input + (long long)(m0 + (lane & 15)) * (NS * ND)
                                           + (long long)(i + 1) * ND
                                           + k0i * 32 + ((lane >> 4) << 3);
                    xp[2 * ii]     = *(const float4*)s;
                    xp[2 * ii + 1] = *(const float4*)(s + 4);
                }
            }
        }
    }
}

extern "C" void kernel_launch(void* const* d_in, const int* in_sizes, int n_in,
                              void* d_out, int out_size, void* d_ws, size_t ws_size,
                              hipStream_t stream) {
    const float* input = (const float*)d_in[0];
    const float* enc_h = (const float*)d_in[1];
    const float* enc_c = (const float*)d_in[2];
    const float* W_ih  = (const float*)d_in[3];
    const float* W_hh  = (const float*)d_in[4];
    const float* b_ih  = (const float*)d_in[5];
    const float* b_hh  = (const float*)d_in[6];
    float* out = (float*)d_out;
    unsigned char* ws = (unsigned char*)d_ws;

    unsigned short* wpk    = (unsigned short*)(ws + WPK_OFF);
    unsigned short* h0base = (unsigned short*)(ws + H0_OFF);
    unsigned short* h1base = (unsigned short*)(ws + H1_OFF);
    unsigned int*   flags  = (unsigned int*)(ws + FLAGS_OFF);

    prep_weights_k<<<2048, 256, 0, stream>>>(W_ih, W_hh, (unsigned int*)wpk);
    prep_state_k<<<128, 256, 0, stream>>>(enc_h, h0base, h1base, flags);
    lstm_persist_k<<<256, 256, 0, stream>>>(input, enc_c, b_ih, b_hh, wpk,
                                            h0base, h1base, out, flags);
}